// Round 1
// 757.041 us; speedup vs baseline: 1.0482x; 1.0482x over previous
//
#include <hip/hip_runtime.h>

typedef unsigned short u16;
typedef unsigned int u32;
typedef unsigned long long u64;

typedef __attribute__((ext_vector_type(8))) __bf16 bf16x8;
typedef __attribute__((ext_vector_type(4))) float f32x4;

// ---------- helpers ----------
__device__ __forceinline__ u16 f2bf(float f) {
  u32 u = __float_as_uint(f);
  u = (u + 0x7fffu + ((u >> 16) & 1u)) >> 16;   // RNE
  return (u16)u;
}
__device__ __forceinline__ float bf2f(u16 h) {
  return __uint_as_float(((u32)h) << 16);
}

__device__ __forceinline__ void stage16(const u16* g, u16* lds_wave_base) {
#if __has_builtin(__builtin_amdgcn_global_load_lds)
  __builtin_amdgcn_global_load_lds((__attribute__((address_space(1))) u32*)g,
                                   (__attribute__((address_space(3))) u32*)lds_wave_base,
                                   16, 0, 0);
#else
  u16* l = lds_wave_base + (threadIdx.x & 63) * 8;
  *(uint4*)l = *(const uint4*)g;
#endif
}

__device__ __forceinline__ float wred(float v) {
  v += __shfl_xor(v, 1, 64);
  v += __shfl_xor(v, 2, 64);
  v += __shfl_xor(v, 4, 64);
  v += __shfl_xor(v, 8, 64);
  v += __shfl_xor(v, 16, 64);
  v += __shfl_xor(v, 32, 64);
  return v;
}

// ---------- fp32 -> bf16 elementwise (weights) ----------
__global__ void __launch_bounds__(256) f2bf_kernel(const float* __restrict__ in,
                                                   u16* __restrict__ out, int n4) {
  int i = blockIdx.x * 256 + threadIdx.x;
  if (i >= n4) return;
  float4 v = ((const float4*)in)[i];
  u64 p = (u64)f2bf(v.x) | ((u64)f2bf(v.y) << 16) | ((u64)f2bf(v.z) << 32) |
          ((u64)f2bf(v.w) << 48);
  ((u64*)out)[i] = p;
}

// ---------- transpose + convert: F[b][f][t] fp32 -> Ft[b][t][f] bf16 ----------
__global__ void __launch_bounds__(256) transpose_bf16(const float* __restrict__ src,
                                                      u16* __restrict__ dst,
                                                      long long fStride, long long oStride) {
  __shared__ float tile[64][65];
  int b = blockIdx.z;
  const float* s = src + (size_t)b * fStride;
  u16* d = dst + (size_t)b * oStride;
  int tid = threadIdx.x;
  int t0 = blockIdx.x * 64, f0 = blockIdx.y * 64;
  int r = tid >> 2, cq = (tid & 3) * 16;
#pragma unroll
  for (int q = 0; q < 4; ++q) {
    float4 v = *(const float4*)(s + (size_t)(f0 + r) * 2048 + (t0 + cq + q * 4));
    tile[r][cq + q * 4 + 0] = v.x;
    tile[r][cq + q * 4 + 1] = v.y;
    tile[r][cq + q * 4 + 2] = v.z;
    tile[r][cq + q * 4 + 3] = v.w;
  }
  __syncthreads();
  u32 ow[8];
#pragma unroll
  for (int h = 0; h < 8; ++h) {
    float lo = tile[cq + 2 * h + 0][r];
    float hi = tile[cq + 2 * h + 1][r];
    ow[h] = (u32)f2bf(lo) | ((u32)f2bf(hi) << 16);
  }
  u16* dp = d + (size_t)(t0 + r) * 2048 + f0 + cq;
  uint4 v0 = {ow[0], ow[1], ow[2], ow[3]};
  uint4 v1 = {ow[4], ow[5], ow[6], ow[7]};
  *(uint4*)dp = v0;
  *(uint4*)(dp + 8) = v1;
}

// ======================================================================
// 256x256 8-phase bf16 GEMM (T2 swizzle + T3/T4 counted vmcnt + T5 setprio)
// Out[b][m][n] = A[b][m][:]·Bw[n][:] + bias[n].  512 thr = 8 waves (2M x 4N).
// LDS: per (kt&1, k-half): 256 rows x 32 cols (64B rows), dbl-buffered = 128 KiB.
// Swizzle: 16B slot p at row r holds logical slot p ^ (r&3); applied as
// inverse-swizzled GLOBAL source (global_load_lds dest stays linear) +
// swizzled ds_read address (rule 21: both-sides-or-neither).
// vmcnt(4) only at phases 4/8 (2 loads/phase/wave, 2 half-tiles in flight).
// ======================================================================
#define BAR() __builtin_amdgcn_s_barrier()
#define LGKM0() asm volatile("s_waitcnt lgkmcnt(0)" ::: "memory")
#define VMC4() asm volatile("s_waitcnt vmcnt(4)" ::: "memory")
#define VMC0() asm volatile("s_waitcnt vmcnt(0)" ::: "memory")

__device__ __forceinline__ void rdA4(const u16 (&sAb)[256][32], int mh, int wm, int ln, int sl,
                                     bf16x8 (&af)[4]) {
#pragma unroll
  for (int mi = 0; mi < 4; ++mi)
    af[mi] = *(const bf16x8*)&sAb[wm * 128 + mh * 64 + mi * 16 + ln][sl];
}
__device__ __forceinline__ void rdB4(const u16 (&sBb)[256][32], int wn, int ln, int sl,
                                     bf16x8 (&bfr)[4]) {
#pragma unroll
  for (int ni = 0; ni < 4; ++ni)
    bfr[ni] = *(const bf16x8*)&sBb[wn * 64 + ni * 16 + ln][sl];
}
__device__ __forceinline__ void mfma8(f32x4 (&acc)[8][4], const bf16x8 (&af)[4],
                                      const bf16x8 (&bfr)[4], int mh) {
  __builtin_amdgcn_s_setprio(1);
#pragma unroll
  for (int mi = 0; mi < 4; ++mi)
#pragma unroll
    for (int ni = 0; ni < 4; ++ni)
      acc[mh * 4 + mi][ni] = __builtin_amdgcn_mfma_f32_16x16x32_bf16(
          af[mi], bfr[ni], acc[mh * 4 + mi][ni], 0, 0, 0);
  __builtin_amdgcn_s_setprio(0);
}
__device__ __forceinline__ void stg2(const u16* g0, const u16* g1, u16 (&dst)[256][32],
                                     int wid, int koff) {
  stage16(g0 + koff, &dst[wid * 32][0]);
  stage16(g1 + koff, &dst[wid * 32 + 16][0]);
}

__global__ void __launch_bounds__(512, 2) gemm8(const u16* __restrict__ A,
                                                const u16* __restrict__ A0,
                                                const u16* __restrict__ Bw,
                                                const float* __restrict__ bias,
                                                u16* __restrict__ Out,
                                                int M, int N, int K) {
  __shared__ u16 sA[2][2][256][32];   // [kt parity][k-half][row][col]
  __shared__ u16 sB[2][2][256][32];
  int tid = threadIdx.x;
  int bz = blockIdx.z;
  int m0 = blockIdx.x * 256, n0 = blockIdx.y * 256;
  const u16* Ab = (bz == 0) ? A0 : (A + (size_t)bz * M * K);
  int lane = tid & 63, wid = tid >> 6;
  int wm = wid >> 2, wn = wid & 3;          // 2 x 4 wave grid
  int ln = lane & 15, lm = lane >> 4;
  int sl = (lm ^ (ln & 3)) * 8;             // swizzled ds_read slot
  int lrow = lane >> 2;                      // staging: row within 16-row chunk
  int swz = (lane & 3) ^ (lrow & 3);         // inverse-swizzled source slot
  const u16* gA0 = Ab + (size_t)(m0 + wid * 32 + lrow) * K + swz * 8;
  const u16* gA1 = gA0 + (size_t)16 * K;
  const u16* gB0 = Bw + (size_t)(n0 + wid * 32 + lrow) * K + swz * 8;
  const u16* gB1 = gB0 + (size_t)16 * K;

  f32x4 acc[8][4];
#pragma unroll
  for (int mi = 0; mi < 8; ++mi)
#pragma unroll
    for (int ni = 0; ni < 4; ++ni) acc[mi][ni] = (f32x4){0.f, 0.f, 0.f, 0.f};

  bf16x8 af[4], bfr[4];

  // prologue: kt0 (both k-halves) + k-half0 of kt1; leave last 2 halves in flight
  stg2(gA0, gA1, sA[0][0], wid, 0);
  stg2(gB0, gB1, sB[0][0], wid, 0);
  stg2(gA0, gA1, sA[0][1], wid, 32);
  stg2(gB0, gB1, sB[0][1], wid, 32);
  stg2(gA0, gA1, sA[1][0], wid, 64);
  stg2(gB0, gB1, sB[1][0], wid, 64);
  VMC4();
  BAR();

  int NI = K >> 7;        // iterations of 2 K-tiles (BK=64) each; K % 128 == 0
  int kt0 = 0;
  for (int I = 0; I < NI - 1; ++I, kt0 += 2) {
    int kb1 = (kt0 + 1) * 64 + 32;
    int kb2 = (kt0 + 2) * 64;
    int kb3 = (kt0 + 2) * 64 + 32;
    int kb4 = (kt0 + 3) * 64;
    // P0: kt0 ks0 mh0 | stage A-kh1(kt0+1)
    rdB4(sB[0][0], wn, ln, sl, bfr);
    rdA4(sA[0][0], 0, wm, ln, sl, af);
    stg2(gA0, gA1, sA[1][1], wid, kb1);
    BAR(); LGKM0(); mfma8(acc, af, bfr, 0); BAR();
    // P1: kt0 ks0 mh1 | stage B-kh1(kt0+1)
    rdA4(sA[0][0], 1, wm, ln, sl, af);
    stg2(gB0, gB1, sB[1][1], wid, kb1);
    BAR(); LGKM0(); mfma8(acc, af, bfr, 1); BAR();
    // P2: kt0 ks1 mh0 | stage A-kh0(kt0+2)
    rdB4(sB[0][1], wn, ln, sl, bfr);
    rdA4(sA[0][1], 0, wm, ln, sl, af);
    stg2(gA0, gA1, sA[0][0], wid, kb2);
    BAR(); LGKM0(); mfma8(acc, af, bfr, 0); BAR();
    // P3: kt0 ks1 mh1 | stage B-kh0(kt0+2) | vmcnt
    rdA4(sA[0][1], 1, wm, ln, sl, af);
    stg2(gB0, gB1, sB[0][0], wid, kb2);
    BAR(); LGKM0(); mfma8(acc, af, bfr, 1);
    VMC4(); BAR();
    // P4: kt1 ks0 mh0 | stage A-kh1(kt0+2)
    rdB4(sB[1][0], wn, ln, sl, bfr);
    rdA4(sA[1][0], 0, wm, ln, sl, af);
    stg2(gA0, gA1, sA[0][1], wid, kb3);
    BAR(); LGKM0(); mfma8(acc, af, bfr, 0); BAR();
    // P5: kt1 ks0 mh1 | stage B-kh1(kt0+2)
    rdA4(sA[1][0], 1, wm, ln, sl, af);
    stg2(gB0, gB1, sB[0][1], wid, kb3);
    BAR(); LGKM0(); mfma8(acc, af, bfr, 1); BAR();
    // P6: kt1 ks1 mh0 | stage A-kh0(kt0+3)
    rdB4(sB[1][1], wn, ln, sl, bfr);
    rdA4(sA[1][1], 0, wm, ln, sl, af);
    stg2(gA0, gA1, sA[1][0], wid, kb4);
    BAR(); LGKM0(); mfma8(acc, af, bfr, 0); BAR();
    // P7: kt1 ks1 mh1 | stage B-kh0(kt0+3) | vmcnt
    rdA4(sA[1][1], 1, wm, ln, sl, af);
    stg2(gB0, gB1, sB[1][0], wid, kb4);
    BAR(); LGKM0(); mfma8(acc, af, bfr, 1);
    VMC4(); BAR();
  }
  // ---- final iteration: only P0/P1 stage (last K-tile's k-half1); drain at P3 ----
  {
    int kb1 = (kt0 + 1) * 64 + 32;
    rdB4(sB[0][0], wn, ln, sl, bfr);
    rdA4(sA[0][0], 0, wm, ln, sl, af);
    stg2(gA0, gA1, sA[1][1], wid, kb1);
    BAR(); LGKM0(); mfma8(acc, af, bfr, 0); BAR();
    rdA4(sA[0][0], 1, wm, ln, sl, af);
    stg2(gB0, gB1, sB[1][1], wid, kb1);
    BAR(); LGKM0(); mfma8(acc, af, bfr, 1); BAR();
    rdB4(sB[0][1], wn, ln, sl, bfr);
    rdA4(sA[0][1], 0, wm, ln, sl, af);
    BAR(); LGKM0(); mfma8(acc, af, bfr, 0); BAR();
    rdA4(sA[0][1], 1, wm, ln, sl, af);
    BAR(); LGKM0(); mfma8(acc, af, bfr, 1);
    VMC0(); BAR();
    rdB4(sB[1][0], wn, ln, sl, bfr);
    rdA4(sA[1][0], 0, wm, ln, sl, af);
    BAR(); LGKM0(); mfma8(acc, af, bfr, 0); BAR();
    rdA4(sA[1][0], 1, wm, ln, sl, af);
    BAR(); LGKM0(); mfma8(acc, af, bfr, 1); BAR();
    rdB4(sB[1][1], wn, ln, sl, bfr);
    rdA4(sA[1][1], 0, wm, ln, sl, af);
    BAR(); LGKM0(); mfma8(acc, af, bfr, 0); BAR();
    rdA4(sA[1][1], 1, wm, ln, sl, af);
    LGKM0(); mfma8(acc, af, bfr, 1);
  }

  // epilogue: bias + bf16 store (C/D map: row = lm*4 + r, col = ln)
  float biasv[4];
#pragma unroll
  for (int ni = 0; ni < 4; ++ni) biasv[ni] = bias[n0 + wn * 64 + ni * 16 + ln];
  u16* ob = Out + (size_t)bz * M * N;
#pragma unroll
  for (int mi = 0; mi < 8; ++mi) {
    int mrow = m0 + wm * 128 + mi * 16 + lm * 4;
#pragma unroll
    for (int ni = 0; ni < 4; ++ni) {
      int ncol = n0 + wn * 64 + ni * 16 + ln;
#pragma unroll
      for (int r = 0; r < 4; ++r)
        ob[(size_t)(mrow + r) * N + ncol] = f2bf(acc[mi][ni][r] + biasv[ni]);
    }
  }
}

// ---------- GroupNorm stats (+apply or +affine-export), [B][T][512] bf16 ----------
template <bool APPLY>
__global__ void __launch_bounds__(1024) gn_kernel(u16* __restrict__ x,
                                                  const float* __restrict__ gamma,
                                                  const float* __restrict__ beta,
                                                  const float* __restrict__ masks,
                                                  float* __restrict__ gmaOut,
                                                  float* __restrict__ gadOut) {
  const int T = 2048;
  int b = blockIdx.x >> 4, gp = blockIdx.x & 15;
  int tid = threadIdx.x;
  int sub = tid & 3, row = tid >> 2;
  int g = sub >> 1;
  u16* base = x + ((size_t)b * T * 512 + gp * 32);
  float s = 0.f, ss = 0.f;
#pragma unroll
  for (int it = 0; it < 8; ++it) {
    int t = it * 256 + row;
    uint4 v = *(const uint4*)(base + (size_t)t * 512 + sub * 8);
    u32 wv[4] = {v.x, v.y, v.z, v.w};
#pragma unroll
    for (int h = 0; h < 4; ++h) {
      float lo = bf2f((u16)(wv[h] & 0xffffu));
      float hi = bf2f((u16)(wv[h] >> 16));
      s += lo + hi;
      ss += lo * lo + hi * hi;
    }
  }
  s += __shfl_xor(s, 1, 64);  ss += __shfl_xor(ss, 1, 64);
  s += __shfl_xor(s, 4, 64);  ss += __shfl_xor(ss, 4, 64);
  s += __shfl_xor(s, 8, 64);  ss += __shfl_xor(ss, 8, 64);
  s += __shfl_xor(s, 16, 64); ss += __shfl_xor(ss, 16, 64);
  s += __shfl_xor(s, 32, 64); ss += __shfl_xor(ss, 32, 64);
  __shared__ float rs[16][2], rss[16][2], mu_s[2], inv_s[2];
  int wv_ = tid >> 6, lane = tid & 63;
  if (lane == 0 || lane == 2) { rs[wv_][g] = s; rss[wv_][g] = ss; }
  __syncthreads();
  if (tid < 2) {
    float S = 0.f, SS = 0.f;
#pragma unroll
    for (int wq = 0; wq < 16; ++wq) { S += rs[wq][tid]; SS += rss[wq][tid]; }
    float cnt = 16.f * (float)T;
    float mu = S / cnt;
    float var = SS / cnt - mu * mu;
    mu_s[tid] = mu;
    inv_s[tid] = rsqrtf(var + 1e-5f);
  }
  __syncthreads();
  if constexpr (APPLY) {
    float mu = mu_s[g], inv = inv_s[g];
    float gm[8], bt[8];
#pragma unroll
    for (int j = 0; j < 8; ++j) {
      int ch = gp * 32 + sub * 8 + j;
      gm[j] = gamma[ch] * inv;
      bt[j] = beta[ch] - mu * gm[j];
    }
#pragma unroll
    for (int it = 0; it < 8; ++it) {
      int t = it * 256 + row;
      u16* p = base + (size_t)t * 512 + sub * 8;
      uint4 v = *(const uint4*)p;
      float mk = masks[(size_t)b * T + t];
      u32 wv2[4] = {v.x, v.y, v.z, v.w};
      u32 ow[4];
#pragma unroll
      for (int h = 0; h < 4; ++h) {
        float lo = bf2f((u16)(wv2[h] & 0xffffu));
        float hi = bf2f((u16)(wv2[h] >> 16));
        lo = (lo * gm[2 * h] + bt[2 * h]) * mk;
        hi = (hi * gm[2 * h + 1] + bt[2 * h + 1]) * mk;
        ow[h] = (u32)f2bf(lo) | ((u32)f2bf(hi) << 16);
      }
      uint4 o4 = {ow[0], ow[1], ow[2], ow[3]};
      *(uint4*)p = o4;
    }
  } else {
    if (tid < 32) {
      int ch = gp * 32 + tid;
      int gg = tid >> 4;
      float gm = gamma[ch] * inv_s[gg];
      gmaOut[(size_t)b * 512 + ch] = gm;
      gadOut[(size_t)b * 512 + ch] = beta[ch] - mu_s[gg] * gm;
    }
  }
}

// ---------- heads v2: Out[b][c][t] = (CLS: sigmoid(mk·dot + bc), else dot) ----------
template <typename TX, bool CLS>
__global__ void __launch_bounds__(512) head_v2(const TX* __restrict__ X,
                                               const float* __restrict__ W,
                                               const float* __restrict__ bcv,
                                               const float* __restrict__ gma,
                                               const float* __restrict__ gad,
                                               const float* __restrict__ masks,
                                               float* __restrict__ Out, int Tdim) {
  __shared__ float red[64 * 20];
  int tid = threadIdx.x;
  int tl = tid & 63;
  int ks = __builtin_amdgcn_readfirstlane(tid >> 6);
  int b = blockIdx.y;
  int t = blockIdx.x * 64 + tl;
  for (int i = tid; i < 64 * 20; i += 512) red[i] = 0.f;
  float acc[20];
#pragma unroll
  for (int c = 0; c < 20; ++c) acc[c] = 0.f;
  const TX* xr = X + ((size_t)b * Tdim + t) * 512 + ks * 64;
  const float* Wk = W + ks * 64;
  const float* gmk = CLS ? (gma + (size_t)b * 512 + ks * 64) : nullptr;
  const float* gak = CLS ? (gad + (size_t)b * 512 + ks * 64) : nullptr;
  __syncthreads();
#pragma unroll
  for (int kk = 0; kk < 64; kk += 8) {
    float xv[8];
    if constexpr (sizeof(TX) == 2) {
      uint4 v = *(const uint4*)(xr + kk);
      u32 wv[4] = {v.x, v.y, v.z, v.w};
#pragma unroll
      for (int h = 0; h < 4; ++h) {
        xv[2 * h] = bf2f((u16)(wv[h] & 0xffffu));
        xv[2 * h + 1] = bf2f((u16)(wv[h] >> 16));
      }
    } else {
      float4 p0 = *(const float4*)(xr + kk);
      float4 p1 = *(const float4*)(xr + kk + 4);
      xv[0] = p0.x; xv[1] = p0.y; xv[2] = p0.z; xv[3] = p0.w;
      xv[4] = p1.x; xv[5] = p1.y; xv[6] = p1.z; xv[7] = p1.w;
    }
    if constexpr (CLS) {
#pragma unroll
      for (int j = 0; j < 8; ++j) xv[j] = xv[j] * gmk[kk + j] + gak[kk + j];
    }
#pragma unroll
    for (int c = 0; c < 20; ++c) {
      const float* wr = &Wk[c * 512 + kk];
#pragma unroll
      for (int j = 0; j < 8; ++j) acc[c] += xv[j] * wr[j];
    }
  }
#pragma unroll
  for (int c = 0; c < 20; ++c) atomicAdd(&red[tl * 20 + c], acc[c]);
  __syncthreads();
  if (tid < 64) {
    float mk = CLS ? masks[(size_t)b * Tdim + t] : 1.f;
#pragma unroll
    for (int c = 0; c < 20; ++c) {
      float v = red[tid * 20 + c];
      if constexpr (CLS) {
        v = v * mk + bcv[c];
        v = 1.f / (1.f + __expf(-v));
      }
      Out[((size_t)b * 20 + c) * Tdim + t] = v;
    }
  }
}

// ---------- top-k mean: bitonic sort 2048 in LDS ----------
__global__ void __launch_bounds__(256) topk_kernel(const float* __restrict__ textL,
                                                   const float* __restrict__ clsL,
                                                   const float* __restrict__ img_masks,
                                                   const float* __restrict__ masks,
                                                   float* __restrict__ out) {
  __shared__ float d[2048];
  __shared__ float rbuf[4];
  int bx = blockIdx.x;
  int head = bx / 320, rem = bx - head * 320;
  int b = rem / 20, c = rem - b * 20;
  int tid = threadIdx.x;
  const float* mk = head ? (masks + (size_t)b * 2048) : (img_masks + (size_t)b * 2048);
  float ls = 0.f;
  for (int i = tid; i < 2048; i += 256) ls += mk[i];
  ls = wred(ls);
  if ((tid & 63) == 0) rbuf[tid >> 6] = ls;
  const float* rowp = (head ? clsL : textL) + ((size_t)(b * 20 + c)) * 2048;
  for (int i = tid; i < 2048; i += 256) d[i] = rowp[i];
  __syncthreads();
  int len = (int)(rbuf[0] + rbuf[1] + rbuf[2] + rbuf[3]);
  int k = len >> 3;
  if (k < 1) k = 1;
  for (int size = 2; size <= 2048; size <<= 1) {
    for (int stride = size >> 1; stride > 0; stride >>= 1) {
      __syncthreads();
      for (int i = tid; i < 2048; i += 256) {
        int j = i ^ stride;
        if (j > i) {
          float a = d[i], bb = d[j];
          bool desc = ((i & size) == 0);
          if (desc ? (a < bb) : (a > bb)) { d[i] = bb; d[j] = a; }
        }
      }
    }
  }
  __syncthreads();
  float ps = 0.f;
  for (int i = tid; i < k; i += 256) ps += d[i];
  ps = wred(ps);
  __syncthreads();
  if ((tid & 63) == 0) rbuf[tid >> 6] = ps;
  __syncthreads();
  if (tid == 0) out[bx] = (rbuf[0] + rbuf[1] + rbuf[2] + rbuf[3]) / (float)k;
}

// ---------- host ----------
extern "C" void kernel_launch(void* const* d_in, const int* in_sizes, int n_in,
                              void* d_out, int out_size, void* d_ws, size_t ws_size,
                              hipStream_t stream) {
  const float* F          = (const float*)d_in[0];   // [16,2048,2048]
  const float* masks      = (const float*)d_in[1];   // [16,1,2048]
  const float* text_proto = (const float*)d_in[2];   // [1,20,512]
  const float* img_feats  = (const float*)d_in[3];   // [16,2048,512]
  const float* img_masks  = (const float*)d_in[4];   // [16,2048]
  const float* W1 = (const float*)d_in[5];
  const float* b1 = (const float*)d_in[6];
  const float* g1 = (const float*)d_in[7];
  const float* be1 = (const float*)d_in[8];
  const float* W2 = (const float*)d_in[9];
  const float* b2 = (const float*)d_in[10];
  const float* g2 = (const float*)d_in[11];
  const float* be2 = (const float*)d_in[12];
  const float* Wc = (const float*)d_in[13];
  const float* bc = (const float*)d_in[14];
  float* out = (float*)d_out;

  const int T = 2048, Fd = 2048, O = 512;
  char* w = (char*)d_ws;
  // carve: W1b[2MB] W2b[.5MB] x1[33.5MB] clsL[2.6MB] textL[2.6MB] gma[32K] gad[32K] | Ft[134MB]
  u16* W1b     = (u16*)(w);
  u16* W2b     = (u16*)(w + 2097152);
  u16* x1      = (u16*)(w + 2621440);
  float* clsL  = (float*)(w + 36175872);
  float* textL = (float*)(w + 38797312);
  float* gma   = (float*)(w + 41418752);
  float* gad   = (float*)(w + 41451520);
  const size_t oEnd0 = 41484288;
  const size_t ftBytes = (size_t)16 * T * Fd * 2;   // 134,217,728

  f2bf_kernel<<<1024, 256, 0, stream>>>(W1, W1b, (O * Fd) / 4);
  f2bf_kernel<<<256, 256, 0, stream>>>(W2, W2b, (O * O) / 4);

  const u16 *FtA, *FtA0;
  u16* x2;
  if (ws_size >= oEnd0 + ftBytes) {
    u16* Ft = (u16*)(w + oEnd0);
    transpose_bf16<<<dim3(32, 32, 16), 256, 0, stream>>>(F, Ft, (long long)Fd * T,
                                                         (long long)T * Fd);
    FtA = Ft; FtA0 = Ft; x2 = Ft;   // x2 aliases Ft (dead after GEMM1)
  } else {
    u16* ft0 = (u16*)(w + oEnd0);
    x2 = (u16*)(w + oEnd0 + (size_t)T * Fd * 2);
    for (int b = 0; b < 16; ++b) {
      u16* dst = (b == 0) ? ft0 : ((u16*)d_in[0]) + (size_t)b * T * Fd;
      transpose_bf16<<<dim3(32, 32, 1), 256, 0, stream>>>(F + (size_t)b * Fd * T, dst, 0, 0);
    }
    FtA = (const u16*)d_in[0]; FtA0 = ft0;
  }

  gemm8<<<dim3(8, 2, 16), 512, 0, stream>>>(FtA, FtA0, W1b, b1, x1, 2048, 512, 2048);
  gn_kernel<true><<<256, 1024, 0, stream>>>(x1, g1, be1, masks, nullptr, nullptr);
  gemm8<<<dim3(8, 2, 16), 512, 0, stream>>>(x1, x1, W2b, b2, x2, 2048, 512, 512);
  gn_kernel<false><<<256, 1024, 0, stream>>>(x2, g2, be2, masks, gma, gad);
  head_v2<u16, true><<<dim3(32, 16), 512, 0, stream>>>(x2, Wc, bc, gma, gad, masks, clsL, 2048);
  head_v2<float, false><<<dim3(32, 16), 512, 0, stream>>>(img_feats, text_proto, nullptr,
                                                          nullptr, nullptr, nullptr, textL, 2048);
  topk_kernel<<<640, 256, 0, stream>>>(textL, clsL, img_masks, masks, out);
}

// Round 2
// 664.388 us; speedup vs baseline: 1.1944x; 1.1395x over previous
//
#include <hip/hip_runtime.h>

typedef unsigned short u16;
typedef unsigned int u32;
typedef unsigned long long u64;

typedef __attribute__((ext_vector_type(8))) __bf16 bf16x8;
typedef __attribute__((ext_vector_type(4))) float f32x4;

// ---------- helpers ----------
__device__ __forceinline__ u16 f2bf(float f) {
  u32 u = __float_as_uint(f);
  u = (u + 0x7fffu + ((u >> 16) & 1u)) >> 16;   // RNE
  return (u16)u;
}
__device__ __forceinline__ float bf2f(u16 h) {
  return __uint_as_float(((u32)h) << 16);
}

__device__ __forceinline__ void stage16(const u16* g, u16* lds_wave_base) {
#if __has_builtin(__builtin_amdgcn_global_load_lds)
  __builtin_amdgcn_global_load_lds((__attribute__((address_space(1))) u32*)g,
                                   (__attribute__((address_space(3))) u32*)lds_wave_base,
                                   16, 0, 0);
#else
  u16* l = lds_wave_base + (threadIdx.x & 63) * 8;
  *(uint4*)l = *(const uint4*)g;
#endif
}

__device__ __forceinline__ float wred(float v) {
  v += __shfl_xor(v, 1, 64);
  v += __shfl_xor(v, 2, 64);
  v += __shfl_xor(v, 4, 64);
  v += __shfl_xor(v, 8, 64);
  v += __shfl_xor(v, 16, 64);
  v += __shfl_xor(v, 32, 64);
  return v;
}

// ---------- fp32 -> bf16 elementwise (weights) ----------
__global__ void __launch_bounds__(256) f2bf_kernel(const float* __restrict__ in,
                                                   u16* __restrict__ out, int n4) {
  int i = blockIdx.x * 256 + threadIdx.x;
  if (i >= n4) return;
  float4 v = ((const float4*)in)[i];
  u64 p = (u64)f2bf(v.x) | ((u64)f2bf(v.y) << 16) | ((u64)f2bf(v.z) << 32) |
          ((u64)f2bf(v.w) << 48);
  ((u64*)out)[i] = p;
}

// ---------- zero small stats buffers ----------
__global__ void __launch_bounds__(256) zinit(float* __restrict__ p, int n) {
  int i = blockIdx.x * 256 + threadIdx.x;
  if (i < n) p[i] = 0.f;
}

// ---------- transpose + convert: F[b][f][t] fp32 -> Ft[b][t][f] bf16 ----------
__global__ void __launch_bounds__(256) transpose_bf16(const float* __restrict__ src,
                                                      u16* __restrict__ dst,
                                                      long long fStride, long long oStride) {
  __shared__ float tile[64][65];
  int b = blockIdx.z;
  const float* s = src + (size_t)b * fStride;
  u16* d = dst + (size_t)b * oStride;
  int tid = threadIdx.x;
  int t0 = blockIdx.x * 64, f0 = blockIdx.y * 64;
  int r = tid >> 2, cq = (tid & 3) * 16;
#pragma unroll
  for (int q = 0; q < 4; ++q) {
    float4 v = *(const float4*)(s + (size_t)(f0 + r) * 2048 + (t0 + cq + q * 4));
    tile[r][cq + q * 4 + 0] = v.x;
    tile[r][cq + q * 4 + 1] = v.y;
    tile[r][cq + q * 4 + 2] = v.z;
    tile[r][cq + q * 4 + 3] = v.w;
  }
  __syncthreads();
  u32 ow[8];
#pragma unroll
  for (int h = 0; h < 8; ++h) {
    float lo = tile[cq + 2 * h + 0][r];
    float hi = tile[cq + 2 * h + 1][r];
    ow[h] = (u32)f2bf(lo) | ((u32)f2bf(hi) << 16);
  }
  u16* dp = d + (size_t)(t0 + r) * 2048 + f0 + cq;
  uint4 v0 = {ow[0], ow[1], ow[2], ow[3]};
  uint4 v1 = {ow[4], ow[5], ow[6], ow[7]};
  *(uint4*)dp = v0;
  *(uint4*)(dp + 8) = v1;
}

// ======================================================================
// 256x256 8-phase bf16 GEMM (T2 swizzle + T3/T4 counted vmcnt + T5 setprio)
// MASKED=false (GEMM1): v = acc + t1[n]        (t1 = b1)
// MASKED=true  (GEMM2): v = (acc + t1[b][n])*mk[t] + t2[n]   (t1 = beta2, t2 = b2)
// Both: epilogue accumulates per-(b,group16) s/ss of v (fp32) via wave-reduce
// + global atomicAdd -> feeds GroupNorm stats without a separate pass.
// ======================================================================
#define BAR() __builtin_amdgcn_s_barrier()
#define LGKM0() asm volatile("s_waitcnt lgkmcnt(0)" ::: "memory")
#define VMC4() asm volatile("s_waitcnt vmcnt(4)" ::: "memory")
#define VMC0() asm volatile("s_waitcnt vmcnt(0)" ::: "memory")

__device__ __forceinline__ void rdA4(const u16 (&sAb)[256][32], int mh, int wm, int ln, int sl,
                                     bf16x8 (&af)[4]) {
#pragma unroll
  for (int mi = 0; mi < 4; ++mi)
    af[mi] = *(const bf16x8*)&sAb[wm * 128 + mh * 64 + mi * 16 + ln][sl];
}
__device__ __forceinline__ void rdB4(const u16 (&sBb)[256][32], int wn, int ln, int sl,
                                     bf16x8 (&bfr)[4]) {
#pragma unroll
  for (int ni = 0; ni < 4; ++ni)
    bfr[ni] = *(const bf16x8*)&sBb[wn * 64 + ni * 16 + ln][sl];
}
__device__ __forceinline__ void mfma8(f32x4 (&acc)[8][4], const bf16x8 (&af)[4],
                                      const bf16x8 (&bfr)[4], int mh) {
  __builtin_amdgcn_s_setprio(1);
#pragma unroll
  for (int mi = 0; mi < 4; ++mi)
#pragma unroll
    for (int ni = 0; ni < 4; ++ni)
      acc[mh * 4 + mi][ni] = __builtin_amdgcn_mfma_f32_16x16x32_bf16(
          af[mi], bfr[ni], acc[mh * 4 + mi][ni], 0, 0, 0);
  __builtin_amdgcn_s_setprio(0);
}
__device__ __forceinline__ void stg2(const u16* g0, const u16* g1, u16 (&dst)[256][32],
                                     int wid, int koff) {
  stage16(g0 + koff, &dst[wid * 32][0]);
  stage16(g1 + koff, &dst[wid * 32 + 16][0]);
}

template <bool MASKED>
__global__ void __launch_bounds__(512, 2) gemm8(const u16* __restrict__ A,
                                                const u16* __restrict__ A0,
                                                const u16* __restrict__ Bw,
                                                size_t bStride,
                                                const float* __restrict__ t1,
                                                const float* __restrict__ t2,
                                                const float* __restrict__ mkp,
                                                float* __restrict__ sOut,
                                                float* __restrict__ ssOut,
                                                u16* __restrict__ Out,
                                                int M, int N, int K) {
  __shared__ u16 sA[2][2][256][32];   // [kt parity][k-half][row][col]
  __shared__ u16 sB[2][2][256][32];
  int tid = threadIdx.x;
  int bz = blockIdx.z;
  int m0 = blockIdx.x * 256, n0 = blockIdx.y * 256;
  const u16* Ab = (bz == 0) ? A0 : (A + (size_t)bz * M * K);
  const u16* Bb = Bw + (size_t)bz * bStride;
  int lane = tid & 63, wid = tid >> 6;
  int wm = wid >> 2, wn = wid & 3;          // 2 x 4 wave grid
  int ln = lane & 15, lm = lane >> 4;
  int sl = (lm ^ (ln & 3)) * 8;             // swizzled ds_read slot
  int lrow = lane >> 2;                      // staging: row within 16-row chunk
  int swz = (lane & 3) ^ (lrow & 3);         // inverse-swizzled source slot
  const u16* gA0 = Ab + (size_t)(m0 + wid * 32 + lrow) * K + swz * 8;
  const u16* gA1 = gA0 + (size_t)16 * K;
  const u16* gB0 = Bb + (size_t)(n0 + wid * 32 + lrow) * K + swz * 8;
  const u16* gB1 = gB0 + (size_t)16 * K;

  f32x4 acc[8][4];
#pragma unroll
  for (int mi = 0; mi < 8; ++mi)
#pragma unroll
    for (int ni = 0; ni < 4; ++ni) acc[mi][ni] = (f32x4){0.f, 0.f, 0.f, 0.f};

  bf16x8 af[4], bfr[4];

  // prologue: kt0 (both k-halves) + k-half0 of kt1; leave last 2 halves in flight
  stg2(gA0, gA1, sA[0][0], wid, 0);
  stg2(gB0, gB1, sB[0][0], wid, 0);
  stg2(gA0, gA1, sA[0][1], wid, 32);
  stg2(gB0, gB1, sB[0][1], wid, 32);
  stg2(gA0, gA1, sA[1][0], wid, 64);
  stg2(gB0, gB1, sB[1][0], wid, 64);
  VMC4();
  BAR();

  int NI = K >> 7;        // iterations of 2 K-tiles (BK=64) each; K % 128 == 0
  int kt0 = 0;
  for (int I = 0; I < NI - 1; ++I, kt0 += 2) {
    int kb1 = (kt0 + 1) * 64 + 32;
    int kb2 = (kt0 + 2) * 64;
    int kb3 = (kt0 + 2) * 64 + 32;
    int kb4 = (kt0 + 3) * 64;
    // P0: kt0 ks0 mh0 | stage A-kh1(kt0+1)
    rdB4(sB[0][0], wn, ln, sl, bfr);
    rdA4(sA[0][0], 0, wm, ln, sl, af);
    stg2(gA0, gA1, sA[1][1], wid, kb1);
    BAR(); LGKM0(); mfma8(acc, af, bfr, 0); BAR();
    // P1: kt0 ks0 mh1 | stage B-kh1(kt0+1)
    rdA4(sA[0][0], 1, wm, ln, sl, af);
    stg2(gB0, gB1, sB[1][1], wid, kb1);
    BAR(); LGKM0(); mfma8(acc, af, bfr, 1); BAR();
    // P2: kt0 ks1 mh0 | stage A-kh0(kt0+2)
    rdB4(sB[0][1], wn, ln, sl, bfr);
    rdA4(sA[0][1], 0, wm, ln, sl, af);
    stg2(gA0, gA1, sA[0][0], wid, kb2);
    BAR(); LGKM0(); mfma8(acc, af, bfr, 0); BAR();
    // P3: kt0 ks1 mh1 | stage B-kh0(kt0+2) | vmcnt
    rdA4(sA[0][1], 1, wm, ln, sl, af);
    stg2(gB0, gB1, sB[0][0], wid, kb2);
    BAR(); LGKM0(); mfma8(acc, af, bfr, 1);
    VMC4(); BAR();
    // P4: kt1 ks0 mh0 | stage A-kh1(kt0+2)
    rdB4(sB[1][0], wn, ln, sl, bfr);
    rdA4(sA[1][0], 0, wm, ln, sl, af);
    stg2(gA0, gA1, sA[0][1], wid, kb3);
    BAR(); LGKM0(); mfma8(acc, af, bfr, 0); BAR();
    // P5: kt1 ks0 mh1 | stage B-kh1(kt0+2)
    rdA4(sA[1][0], 1, wm, ln, sl, af);
    stg2(gB0, gB1, sB[0][1], wid, kb3);
    BAR(); LGKM0(); mfma8(acc, af, bfr, 1); BAR();
    // P6: kt1 ks1 mh0 | stage A-kh0(kt0+3)
    rdB4(sB[1][1], wn, ln, sl, bfr);
    rdA4(sA[1][1], 0, wm, ln, sl, af);
    stg2(gA0, gA1, sA[1][0], wid, kb4);
    BAR(); LGKM0(); mfma8(acc, af, bfr, 0); BAR();
    // P7: kt1 ks1 mh1 | stage B-kh0(kt0+3) | vmcnt
    rdA4(sA[1][1], 1, wm, ln, sl, af);
    stg2(gB0, gB1, sB[1][0], wid, kb4);
    BAR(); LGKM0(); mfma8(acc, af, bfr, 1);
    VMC4(); BAR();
  }
  // ---- final iteration: only P0/P1 stage (last K-tile's k-half1); drain at P3 ----
  {
    int kb1 = (kt0 + 1) * 64 + 32;
    rdB4(sB[0][0], wn, ln, sl, bfr);
    rdA4(sA[0][0], 0, wm, ln, sl, af);
    stg2(gA0, gA1, sA[1][1], wid, kb1);
    BAR(); LGKM0(); mfma8(acc, af, bfr, 0); BAR();
    rdA4(sA[0][0], 1, wm, ln, sl, af);
    stg2(gB0, gB1, sB[1][1], wid, kb1);
    BAR(); LGKM0(); mfma8(acc, af, bfr, 1); BAR();
    rdB4(sB[0][1], wn, ln, sl, bfr);
    rdA4(sA[0][1], 0, wm, ln, sl, af);
    BAR(); LGKM0(); mfma8(acc, af, bfr, 0); BAR();
    rdA4(sA[0][1], 1, wm, ln, sl, af);
    BAR(); LGKM0(); mfma8(acc, af, bfr, 1);
    VMC0(); BAR();
    rdB4(sB[1][0], wn, ln, sl, bfr);
    rdA4(sA[1][0], 0, wm, ln, sl, af);
    BAR(); LGKM0(); mfma8(acc, af, bfr, 0); BAR();
    rdA4(sA[1][0], 1, wm, ln, sl, af);
    BAR(); LGKM0(); mfma8(acc, af, bfr, 1); BAR();
    rdB4(sB[1][1], wn, ln, sl, bfr);
    rdA4(sA[1][1], 0, wm, ln, sl, af);
    BAR(); LGKM0(); mfma8(acc, af, bfr, 0); BAR();
    rdA4(sA[1][1], 1, wm, ln, sl, af);
    LGKM0(); mfma8(acc, af, bfr, 1);
  }

  // ---- epilogue: per-n terms + optional mask, bf16 store, GN partial stats ----
  const float* t1p = MASKED ? (t1 + (size_t)bz * N) : t1;
  float t1v[4], t2v[4];
#pragma unroll
  for (int ni = 0; ni < 4; ++ni) {
    int ncol = n0 + wn * 64 + ni * 16 + ln;
    t1v[ni] = t1p[ncol];
    t2v[ni] = MASKED ? t2[ncol] : 0.f;
  }
  float sp[4] = {0.f, 0.f, 0.f, 0.f}, ssp[4] = {0.f, 0.f, 0.f, 0.f};
  u16* ob = Out + (size_t)bz * M * N;
#pragma unroll
  for (int mi = 0; mi < 8; ++mi) {
    int mrow = m0 + wm * 128 + mi * 16 + lm * 4;
    float mka[4] = {1.f, 1.f, 1.f, 1.f};
    if constexpr (MASKED) {
      float4 mv = *(const float4*)(mkp + (size_t)bz * M + mrow);
      mka[0] = mv.x; mka[1] = mv.y; mka[2] = mv.z; mka[3] = mv.w;
    }
#pragma unroll
    for (int ni = 0; ni < 4; ++ni) {
      int ncol = n0 + wn * 64 + ni * 16 + ln;
#pragma unroll
      for (int r = 0; r < 4; ++r) {
        float v = acc[mi][ni][r] + t1v[ni];
        if constexpr (MASKED) v = v * mka[r] + t2v[ni];
        sp[ni] += v;
        ssp[ni] += v * v;
        ob[(size_t)(mrow + r) * N + ncol] = f2bf(v);
      }
    }
  }
#pragma unroll
  for (int ni = 0; ni < 4; ++ni) {
    float S = wred(sp[ni]);
    float SS = wred(ssp[ni]);
    if (lane == 0) {
      int grp = blockIdx.y * 16 + wn * 4 + ni;   // = channel/16
      atomicAdd(&sOut[bz * 32 + grp], S);
      atomicAdd(&ssOut[bz * 32 + grp], SS);
    }
  }
}

// ---------- stats -> per-channel affine (gm = gamma*inv, gd = beta - mu*gm) ----------
__global__ void __launch_bounds__(512) gnstats(const float* __restrict__ sS,
                                               const float* __restrict__ sSS,
                                               const float* __restrict__ gamma,
                                               const float* __restrict__ beta,
                                               float* __restrict__ gmO,
                                               float* __restrict__ gdO) {
  int b = blockIdx.x;
  int c = threadIdx.x;
  int g = c >> 4;
  const float cnt = 16.f * 2048.f;
  float mu = sS[b * 32 + g] / cnt;
  float var = sSS[b * 32 + g] / cnt - mu * mu;
  float inv = rsqrtf(var + 1e-5f);
  float gm = gamma[c] * inv;
  gmO[(size_t)b * 512 + c] = gm;
  gdO[(size_t)b * 512 + c] = beta[c] - mu * gm;
}

// ---------- fold GN1 affine into W2: W2f[b][o][c] = bf16(W2[o][c]*gm1[b][c]),
// beta2[b][o] = sum_c W2[o][c]*bt1[b][c].  One wave per (b,o). ----------
__global__ void __launch_bounds__(256) wfold(const float* __restrict__ W2,
                                             const float* __restrict__ gm1,
                                             const float* __restrict__ bt1,
                                             u16* __restrict__ W2f,
                                             float* __restrict__ beta2) {
  int w = blockIdx.x * 4 + (threadIdx.x >> 6);
  int lane = threadIdx.x & 63;
  int b = w >> 9, o = w & 511;
  const float* wr = W2 + (size_t)o * 512 + lane * 8;
  const float* gmr = gm1 + (size_t)b * 512 + lane * 8;
  const float* btr = bt1 + (size_t)b * 512 + lane * 8;
  float4 w0 = *(const float4*)wr, w1 = *(const float4*)(wr + 4);
  float4 g0 = *(const float4*)gmr, g1v = *(const float4*)(gmr + 4);
  float4 t0 = *(const float4*)btr, t1v = *(const float4*)(btr + 4);
  float wv[8] = {w0.x, w0.y, w0.z, w0.w, w1.x, w1.y, w1.z, w1.w};
  float gv[8] = {g0.x, g0.y, g0.z, g0.w, g1v.x, g1v.y, g1v.z, g1v.w};
  float tv[8] = {t0.x, t0.y, t0.z, t0.w, t1v.x, t1v.y, t1v.z, t1v.w};
  u32 ow[4];
  float acc = 0.f;
#pragma unroll
  for (int h = 0; h < 4; ++h) {
    float lo = wv[2 * h] * gv[2 * h];
    float hi = wv[2 * h + 1] * gv[2 * h + 1];
    ow[h] = (u32)f2bf(lo) | ((u32)f2bf(hi) << 16);
    acc += wv[2 * h] * tv[2 * h] + wv[2 * h + 1] * tv[2 * h + 1];
  }
  uint4 o4 = {ow[0], ow[1], ow[2], ow[3]};
  *(uint4*)(W2f + ((size_t)b * 512 + o) * 512 + lane * 8) = o4;
  acc = wred(acc);
  if (lane == 0) beta2[(size_t)b * 512 + o] = acc;
}

// ---------- heads v2: Out[b][c][t] = (CLS: sigmoid(mk·dot + bc), else dot) ----------
template <typename TX, bool CLS>
__global__ void __launch_bounds__(512) head_v2(const TX* __restrict__ X,
                                               const float* __restrict__ W,
                                               const float* __restrict__ bcv,
                                               const float* __restrict__ gma,
                                               const float* __restrict__ gad,
                                               const float* __restrict__ masks,
                                               float* __restrict__ Out, int Tdim) {
  __shared__ float red[64 * 20];
  int tid = threadIdx.x;
  int tl = tid & 63;
  int ks = __builtin_amdgcn_readfirstlane(tid >> 6);
  int b = blockIdx.y;
  int t = blockIdx.x * 64 + tl;
  for (int i = tid; i < 64 * 20; i += 512) red[i] = 0.f;
  float acc[20];
#pragma unroll
  for (int c = 0; c < 20; ++c) acc[c] = 0.f;
  const TX* xr = X + ((size_t)b * Tdim + t) * 512 + ks * 64;
  const float* Wk = W + ks * 64;
  const float* gmk = CLS ? (gma + (size_t)b * 512 + ks * 64) : nullptr;
  const float* gak = CLS ? (gad + (size_t)b * 512 + ks * 64) : nullptr;
  __syncthreads();
#pragma unroll
  for (int kk = 0; kk < 64; kk += 8) {
    float xv[8];
    if constexpr (sizeof(TX) == 2) {
      uint4 v = *(const uint4*)(xr + kk);
      u32 wv[4] = {v.x, v.y, v.z, v.w};
#pragma unroll
      for (int h = 0; h < 4; ++h) {
        xv[2 * h] = bf2f((u16)(wv[h] & 0xffffu));
        xv[2 * h + 1] = bf2f((u16)(wv[h] >> 16));
      }
    } else {
      float4 p0 = *(const float4*)(xr + kk);
      float4 p1 = *(const float4*)(xr + kk + 4);
      xv[0] = p0.x; xv[1] = p0.y; xv[2] = p0.z; xv[3] = p0.w;
      xv[4] = p1.x; xv[5] = p1.y; xv[6] = p1.z; xv[7] = p1.w;
    }
    if constexpr (CLS) {
#pragma unroll
      for (int j = 0; j < 8; ++j) xv[j] = xv[j] * gmk[kk + j] + gak[kk + j];
    }
#pragma unroll
    for (int c = 0; c < 20; ++c) {
      const float* wr = &Wk[c * 512 + kk];
#pragma unroll
      for (int j = 0; j < 8; ++j) acc[c] += xv[j] * wr[j];
    }
  }
#pragma unroll
  for (int c = 0; c < 20; ++c) atomicAdd(&red[tl * 20 + c], acc[c]);
  __syncthreads();
  if (tid < 64) {
    float mk = CLS ? masks[(size_t)b * Tdim + t] : 1.f;
#pragma unroll
    for (int c = 0; c < 20; ++c) {
      float v = red[tid * 20 + c];
      if constexpr (CLS) {
        v = v * mk + bcv[c];
        v = 1.f / (1.f + __expf(-v));
      }
      Out[((size_t)b * 20 + c) * Tdim + t] = v;
    }
  }
}

// ---------- top-k mean via exact MSB radix-select (4x 8-bit passes) ----------
__global__ void __launch_bounds__(256) topk_sel(const float* __restrict__ textL,
                                                const float* __restrict__ clsL,
                                                const float* __restrict__ img_masks,
                                                const float* __restrict__ masks,
                                                float* __restrict__ out) {
  __shared__ u32 keys[2048];
  __shared__ u32 hist[256];
  __shared__ u32 sel[2];
  __shared__ float rbuf[4], rbuf2[4];
  int bx = blockIdx.x;
  int head = bx / 320, rem = bx - head * 320;
  int b = rem / 20, c = rem - b * 20;
  int tid = threadIdx.x;
  const float* mk = head ? (masks + (size_t)b * 2048) : (img_masks + (size_t)b * 2048);
  float ls = 0.f;
  for (int i = tid; i < 2048; i += 256) ls += mk[i];
  ls = wred(ls);
  if ((tid & 63) == 0) rbuf[tid >> 6] = ls;
  const float* rowp = (head ? clsL : textL) + ((size_t)(b * 20 + c)) * 2048;
  for (int i = tid; i < 2048; i += 256) {
    u32 u = __float_as_uint(rowp[i]);
    u32 sgn = (u32)((int)u >> 31);
    keys[i] = u ^ (sgn | 0x80000000u);   // monotone flip: larger float -> larger uint
  }
  __syncthreads();
  int len = (int)(rbuf[0] + rbuf[1] + rbuf[2] + rbuf[3]);
  u32 k = (u32)(len >> 3);
  if (k < 1) k = 1;
  u32 want = k, prefix = 0;
#pragma unroll
  for (int byt = 3; byt >= 0; --byt) {
    int sh = byt * 8;
    hist[tid] = 0;
    __syncthreads();
    for (int i = tid; i < 2048; i += 256) {
      u32 kk = keys[i];
      bool match = (byt == 3) || ((kk >> (sh + 8)) == (prefix >> (sh + 8)));
      if (match) atomicAdd(&hist[(kk >> sh) & 0xffu], 1u);
    }
    __syncthreads();
    if (tid < 64) {   // single-wave suffix scan over 256 bins (descending)
      int r0 = tid * 4;
      u32 h0 = hist[255 - r0], h1 = hist[254 - r0], h2 = hist[253 - r0], h3 = hist[252 - r0];
      u32 p0 = h0, p1 = p0 + h1, p2 = p1 + h2, p3 = p2 + h3;
      u32 inc = p3;
#pragma unroll
      for (int off = 1; off < 64; off <<= 1) {
        u32 t = __shfl_up(inc, off, 64);
        if (tid >= off) inc += t;
      }
      u32 excl = inc - p3;
      u32 S0 = excl + p0, S1 = excl + p1, S2 = excl + p2, S3 = excl + p3;
      if (S0 >= want && excl < want) { sel[0] = (u32)(255 - r0); sel[1] = want - excl; }
      if (S1 >= want && S0 < want)   { sel[0] = (u32)(254 - r0); sel[1] = want - S0; }
      if (S2 >= want && S1 < want)   { sel[0] = (u32)(253 - r0); sel[1] = want - S1; }
      if (S3 >= want && S2 < want)   { sel[0] = (u32)(252 - r0); sel[1] = want - S2; }
    }
    __syncthreads();
    prefix |= sel[0] << sh;
    want = sel[1];
    __syncthreads();
  }
  // prefix == exact k-th largest key. sum strictly-greater + ties at threshold.
  float s = 0.f, cg = 0.f;
  for (int i = tid; i < 2048; i += 256) {
    u32 kk = keys[i];
    if (kk > prefix) {
      u32 u = (kk & 0x80000000u) ? (kk ^ 0x80000000u) : ~kk;
      s += __uint_as_float(u);
      cg += 1.f;
    }
  }
  s = wred(s);
  cg = wred(cg);
  if ((tid & 63) == 0) { rbuf[tid >> 6] = s; rbuf2[tid >> 6] = cg; }
  __syncthreads();
  if (tid == 0) {
    float S = rbuf[0] + rbuf[1] + rbuf[2] + rbuf[3];
    float CG = rbuf2[0] + rbuf2[1] + rbuf2[2] + rbuf2[3];
    u32 u = (prefix & 0x80000000u) ? (prefix ^ 0x80000000u) : ~prefix;
    float thr = __uint_as_float(u);
    S += ((float)k - CG) * thr;
    out[bx] = S / (float)k;
  }
}

// ---------- host ----------
extern "C" void kernel_launch(void* const* d_in, const int* in_sizes, int n_in,
                              void* d_out, int out_size, void* d_ws, size_t ws_size,
                              hipStream_t stream) {
  const float* F          = (const float*)d_in[0];   // [16,2048,2048]
  const float* masks      = (const float*)d_in[1];   // [16,1,2048]
  const float* text_proto = (const float*)d_in[2];   // [1,20,512]
  const float* img_feats  = (const float*)d_in[3];   // [16,2048,512]
  const float* img_masks  = (const float*)d_in[4];   // [16,2048]
  const float* W1 = (const float*)d_in[5];
  const float* b1 = (const float*)d_in[6];
  const float* g1 = (const float*)d_in[7];
  const float* be1 = (const float*)d_in[8];
  const float* W2 = (const float*)d_in[9];
  const float* b2 = (const float*)d_in[10];
  const float* g2 = (const float*)d_in[11];
  const float* be2 = (const float*)d_in[12];
  const float* Wc = (const float*)d_in[13];
  const float* bc = (const float*)d_in[14];
  float* out = (float*)d_out;

  const int T = 2048, Fd = 2048, O = 512;
  char* w = (char*)d_ws;
  // carve: W1b[2MB] (unused .5MB) x1[33.5MB] clsL[2.6MB] textL[2.6MB] gma[32K] gad[32K] | Ft[134MB] | ext
  u16* W1b     = (u16*)(w);
  u16* x1      = (u16*)(w + 2621440);
  float* clsL  = (float*)(w + 36175872);
  float* textL = (float*)(w + 38797312);
  float* gma   = (float*)(w + 41418752);
  float* gad   = (float*)(w + 41451520);
  const size_t oEnd0 = 41484288;
  const size_t ftBytes = (size_t)16 * T * Fd * 2;   // 134,217,728
  const size_t EXTRA = 8388608 + 3 * 32768 + 8192;  // W2f + gm1/bt1/beta2 + stats

  bool bigws = ws_size >= oEnd0 + ftBytes + EXTRA;
  char* ext = bigws ? (w + oEnd0 + ftBytes)
                    : (w + oEnd0 + (size_t)T * Fd * 2 + (size_t)16 * T * O * 2);
  u16* W2f    = (u16*)ext;
  float* gm1  = (float*)(ext + 8388608);
  float* bt1  = gm1 + 16 * 512;
  float* beta2 = bt1 + 16 * 512;
  float* sbase = beta2 + 16 * 512;   // s1|ss1|s2|ss2, 512 floats each
  float* s1 = sbase, *ss1 = sbase + 512, *s2 = sbase + 1024, *ss2 = sbase + 1536;

  f2bf_kernel<<<1024, 256, 0, stream>>>(W1, W1b, (O * Fd) / 4);
  zinit<<<8, 256, 0, stream>>>(sbase, 2048);

  const u16 *FtA, *FtA0;
  u16* x2;
  if (bigws) {
    u16* Ft = (u16*)(w + oEnd0);
    transpose_bf16<<<dim3(32, 32, 16), 256, 0, stream>>>(F, Ft, (long long)Fd * T,
                                                         (long long)T * Fd);
    FtA = Ft; FtA0 = Ft; x2 = Ft;   // x2 aliases Ft (dead after GEMM1)
  } else {
    u16* ft0 = (u16*)(w + oEnd0);
    x2 = (u16*)(w + oEnd0 + (size_t)T * Fd * 2);
    for (int b = 0; b < 16; ++b) {
      u16* dst = (b == 0) ? ft0 : ((u16*)d_in[0]) + (size_t)b * T * Fd;
      transpose_bf16<<<dim3(32, 32, 1), 256, 0, stream>>>(F + (size_t)b * Fd * T, dst, 0, 0);
    }
    FtA = (const u16*)d_in[0]; FtA0 = ft0;
  }

  gemm8<false><<<dim3(8, 2, 16), 512, 0, stream>>>(FtA, FtA0, W1b, 0, b1, nullptr, nullptr,
                                                   s1, ss1, x1, 2048, 512, 2048);
  gnstats<<<16, 512, 0, stream>>>(s1, ss1, g1, be1, gm1, bt1);
  wfold<<<2048, 256, 0, stream>>>(W2, gm1, bt1, W2f, beta2);
  gemm8<true><<<dim3(8, 2, 16), 512, 0, stream>>>(x1, x1, W2f, (size_t)512 * 512, beta2, b2,
                                                  masks, s2, ss2, x2, 2048, 512, 512);
  gnstats<<<16, 512, 0, stream>>>(s2, ss2, g2, be2, gma, gad);
  head_v2<u16, true><<<dim3(32, 16), 512, 0, stream>>>(x2, Wc, bc, gma, gad, masks, clsL, 2048);
  head_v2<float, false><<<dim3(32, 16), 512, 0, stream>>>(img_feats, text_proto, nullptr,
                                                          nullptr, nullptr, nullptr, textL, 2048);
  topk_sel<<<640, 256, 0, stream>>>(textL, clsL, img_masks, masks, out);
}

// Round 3
// 618.646 us; speedup vs baseline: 1.2827x; 1.0739x over previous
//
#include <hip/hip_runtime.h>

typedef unsigned short u16;
typedef unsigned int u32;
typedef unsigned long long u64;

typedef __attribute__((ext_vector_type(8))) __bf16 bf16x8;
typedef __attribute__((ext_vector_type(4))) float f32x4;

// ---------- helpers ----------
__device__ __forceinline__ u16 f2bf(float f) {
  u32 u = __float_as_uint(f);
  u = (u + 0x7fffu + ((u >> 16) & 1u)) >> 16;   // RNE
  return (u16)u;
}
__device__ __forceinline__ float bf2f(u16 h) {
  return __uint_as_float(((u32)h) << 16);
}

__device__ __forceinline__ void stage16(const u16* g, u16* lds_wave_base) {
#if __has_builtin(__builtin_amdgcn_global_load_lds)
  __builtin_amdgcn_global_load_lds((__attribute__((address_space(1))) u32*)g,
                                   (__attribute__((address_space(3))) u32*)lds_wave_base,
                                   16, 0, 0);
#else
  u16* l = lds_wave_base + (threadIdx.x & 63) * 8;
  *(uint4*)l = *(const uint4*)g;
#endif
}

__device__ __forceinline__ float wred(float v) {
  v += __shfl_xor(v, 1, 64);
  v += __shfl_xor(v, 2, 64);
  v += __shfl_xor(v, 4, 64);
  v += __shfl_xor(v, 8, 64);
  v += __shfl_xor(v, 16, 64);
  v += __shfl_xor(v, 32, 64);
  return v;
}

// ---------- fp32 -> bf16 elementwise (weights) [fallback path only] ----------
__global__ void __launch_bounds__(256) f2bf_kernel(const float* __restrict__ in,
                                                   u16* __restrict__ out, int n4) {
  int i = blockIdx.x * 256 + threadIdx.x;
  if (i >= n4) return;
  float4 v = ((const float4*)in)[i];
  u64 p = (u64)f2bf(v.x) | ((u64)f2bf(v.y) << 16) | ((u64)f2bf(v.z) << 32) |
          ((u64)f2bf(v.w) << 48);
  ((u64*)out)[i] = p;
}

// ---------- zero small stats buffers [fallback path only] ----------
__global__ void __launch_bounds__(256) zinit(float* __restrict__ p, int n) {
  int i = blockIdx.x * 256 + threadIdx.x;
  if (i < n) p[i] = 0.f;
}

// ---------- transpose + convert: F[b][f][t] fp32 -> Ft[b][t][f] bf16 [fallback] ----------
__global__ void __launch_bounds__(256) transpose_bf16(const float* __restrict__ src,
                                                      u16* __restrict__ dst,
                                                      long long fStride, long long oStride) {
  __shared__ float tile[64][65];
  int b = blockIdx.z;
  const float* s = src + (size_t)b * fStride;
  u16* d = dst + (size_t)b * oStride;
  int tid = threadIdx.x;
  int t0 = blockIdx.x * 64, f0 = blockIdx.y * 64;
  int r = tid >> 2, cq = (tid & 3) * 16;
#pragma unroll
  for (int q = 0; q < 4; ++q) {
    float4 v = *(const float4*)(s + (size_t)(f0 + r) * 2048 + (t0 + cq + q * 4));
    tile[r][cq + q * 4 + 0] = v.x;
    tile[r][cq + q * 4 + 1] = v.y;
    tile[r][cq + q * 4 + 2] = v.z;
    tile[r][cq + q * 4 + 3] = v.w;
  }
  __syncthreads();
  u32 ow[8];
#pragma unroll
  for (int h = 0; h < 8; ++h) {
    float lo = tile[cq + 2 * h + 0][r];
    float hi = tile[cq + 2 * h + 1][r];
    ow[h] = (u32)f2bf(lo) | ((u32)f2bf(hi) << 16);
  }
  u16* dp = d + (size_t)(t0 + r) * 2048 + f0 + cq;
  uint4 v0 = {ow[0], ow[1], ow[2], ow[3]};
  uint4 v1 = {ow[4], ow[5], ow[6], ow[7]};
  *(uint4*)dp = v0;
  *(uint4*)(dp + 8) = v1;
}

// ---------- merged prep: transpose (z<16) + W1 f2bf + stats-zero (z==16) ----------
__global__ void __launch_bounds__(256) prep_kernel(const float* __restrict__ F,
                                                   u16* __restrict__ Ft,
                                                   const float* __restrict__ W1,
                                                   u16* __restrict__ W1b,
                                                   float* __restrict__ sbase) {
  if (blockIdx.z == 16) {
    int bid = blockIdx.y * 32 + blockIdx.x;
    int tid = threadIdx.x;
    if (bid == 0) {
      for (int q = tid; q < 2048; q += 256) sbase[q] = 0.f;
    }
    int i = bid * 256 + tid;   // exactly 262144 = (512*2048)/4
    float4 v = ((const float4*)W1)[i];
    u64 p = (u64)f2bf(v.x) | ((u64)f2bf(v.y) << 16) | ((u64)f2bf(v.z) << 32) |
            ((u64)f2bf(v.w) << 48);
    ((u64*)W1b)[i] = p;
    return;
  }
  __shared__ float tile[64][65];
  int b = blockIdx.z;
  const float* s = F + (size_t)b * 2048 * 2048;
  u16* d = Ft + (size_t)b * 2048 * 2048;
  int tid = threadIdx.x;
  int t0 = blockIdx.x * 64, f0 = blockIdx.y * 64;
  int r = tid >> 2, cq = (tid & 3) * 16;
#pragma unroll
  for (int q = 0; q < 4; ++q) {
    float4 v = *(const float4*)(s + (size_t)(f0 + r) * 2048 + (t0 + cq + q * 4));
    tile[r][cq + q * 4 + 0] = v.x;
    tile[r][cq + q * 4 + 1] = v.y;
    tile[r][cq + q * 4 + 2] = v.z;
    tile[r][cq + q * 4 + 3] = v.w;
  }
  __syncthreads();
  u32 ow[8];
#pragma unroll
  for (int h = 0; h < 8; ++h) {
    float lo = tile[cq + 2 * h + 0][r];
    float hi = tile[cq + 2 * h + 1][r];
    ow[h] = (u32)f2bf(lo) | ((u32)f2bf(hi) << 16);
  }
  u16* dp = d + (size_t)(t0 + r) * 2048 + f0 + cq;
  uint4 v0 = {ow[0], ow[1], ow[2], ow[3]};
  uint4 v1 = {ow[4], ow[5], ow[6], ow[7]};
  *(uint4*)dp = v0;
  *(uint4*)(dp + 8) = v1;
}

// ======================================================================
// 256x256 8-phase bf16 GEMM (T2 swizzle + T3/T4 counted vmcnt + T5 setprio)
// MASKED=false (GEMM1): v = acc + t1[n]        (t1 = b1)
// MASKED=true  (GEMM2): v = (acc + t1[b][n])*mk[t] + t2[n]   (t1 = beta2, t2 = b2)
// Both: epilogue accumulates per-(b,group16) s/ss of v (fp32) via wave-reduce
// + global atomicAdd -> feeds GroupNorm stats without a separate pass.
// ======================================================================
#define BAR() __builtin_amdgcn_s_barrier()
#define LGKM0() asm volatile("s_waitcnt lgkmcnt(0)" ::: "memory")
#define VMC4() asm volatile("s_waitcnt vmcnt(4)" ::: "memory")
#define VMC0() asm volatile("s_waitcnt vmcnt(0)" ::: "memory")

__device__ __forceinline__ void rdA4(const u16 (&sAb)[256][32], int mh, int wm, int ln, int sl,
                                     bf16x8 (&af)[4]) {
#pragma unroll
  for (int mi = 0; mi < 4; ++mi)
    af[mi] = *(const bf16x8*)&sAb[wm * 128 + mh * 64 + mi * 16 + ln][sl];
}
__device__ __forceinline__ void rdB4(const u16 (&sBb)[256][32], int wn, int ln, int sl,
                                     bf16x8 (&bfr)[4]) {
#pragma unroll
  for (int ni = 0; ni < 4; ++ni)
    bfr[ni] = *(const bf16x8*)&sBb[wn * 64 + ni * 16 + ln][sl];
}
__device__ __forceinline__ void mfma8(f32x4 (&acc)[8][4], const bf16x8 (&af)[4],
                                      const bf16x8 (&bfr)[4], int mh) {
  __builtin_amdgcn_s_setprio(1);
#pragma unroll
  for (int mi = 0; mi < 4; ++mi)
#pragma unroll
    for (int ni = 0; ni < 4; ++ni)
      acc[mh * 4 + mi][ni] = __builtin_amdgcn_mfma_f32_16x16x32_bf16(
          af[mi], bfr[ni], acc[mh * 4 + mi][ni], 0, 0, 0);
  __builtin_amdgcn_s_setprio(0);
}
__device__ __forceinline__ void stg2(const u16* g0, const u16* g1, u16 (&dst)[256][32],
                                     int wid, int koff) {
  stage16(g0 + koff, &dst[wid * 32][0]);
  stage16(g1 + koff, &dst[wid * 32 + 16][0]);
}

template <bool MASKED>
__global__ void __launch_bounds__(512, 2) gemm8(const u16* __restrict__ A,
                                                const u16* __restrict__ A0,
                                                const u16* __restrict__ Bw,
                                                size_t bStride,
                                                const float* __restrict__ t1,
                                                const float* __restrict__ t2,
                                                const float* __restrict__ mkp,
                                                float* __restrict__ sOut,
                                                float* __restrict__ ssOut,
                                                u16* __restrict__ Out,
                                                int M, int N, int K) {
  __shared__ u16 sA[2][2][256][32];   // [kt parity][k-half][row][col]
  __shared__ u16 sB[2][2][256][32];
  int tid = threadIdx.x;
  int bz = blockIdx.z;
  int m0 = blockIdx.x * 256, n0 = blockIdx.y * 256;
  const u16* Ab = (bz == 0) ? A0 : (A + (size_t)bz * M * K);
  const u16* Bb = Bw + (size_t)bz * bStride;
  int lane = tid & 63, wid = tid >> 6;
  int wm = wid >> 2, wn = wid & 3;          // 2 x 4 wave grid
  int ln = lane & 15, lm = lane >> 4;
  int sl = (lm ^ (ln & 3)) * 8;             // swizzled ds_read slot
  int lrow = lane >> 2;                      // staging: row within 16-row chunk
  int swz = (lane & 3) ^ (lrow & 3);         // inverse-swizzled source slot
  const u16* gA0 = Ab + (size_t)(m0 + wid * 32 + lrow) * K + swz * 8;
  const u16* gA1 = gA0 + (size_t)16 * K;
  const u16* gB0 = Bb + (size_t)(n0 + wid * 32 + lrow) * K + swz * 8;
  const u16* gB1 = gB0 + (size_t)16 * K;

  f32x4 acc[8][4];
#pragma unroll
  for (int mi = 0; mi < 8; ++mi)
#pragma unroll
    for (int ni = 0; ni < 4; ++ni) acc[mi][ni] = (f32x4){0.f, 0.f, 0.f, 0.f};

  bf16x8 af[4], bfr[4];

  // prologue: kt0 (both k-halves) + k-half0 of kt1; leave last 2 halves in flight
  stg2(gA0, gA1, sA[0][0], wid, 0);
  stg2(gB0, gB1, sB[0][0], wid, 0);
  stg2(gA0, gA1, sA[0][1], wid, 32);
  stg2(gB0, gB1, sB[0][1], wid, 32);
  stg2(gA0, gA1, sA[1][0], wid, 64);
  stg2(gB0, gB1, sB[1][0], wid, 64);
  VMC4();
  BAR();

  int NI = K >> 7;        // iterations of 2 K-tiles (BK=64) each; K % 128 == 0
  int kt0 = 0;
  for (int I = 0; I < NI - 1; ++I, kt0 += 2) {
    int kb1 = (kt0 + 1) * 64 + 32;
    int kb2 = (kt0 + 2) * 64;
    int kb3 = (kt0 + 2) * 64 + 32;
    int kb4 = (kt0 + 3) * 64;
    // P0: kt0 ks0 mh0 | stage A-kh1(kt0+1)
    rdB4(sB[0][0], wn, ln, sl, bfr);
    rdA4(sA[0][0], 0, wm, ln, sl, af);
    stg2(gA0, gA1, sA[1][1], wid, kb1);
    BAR(); LGKM0(); mfma8(acc, af, bfr, 0); BAR();
    // P1: kt0 ks0 mh1 | stage B-kh1(kt0+1)
    rdA4(sA[0][0], 1, wm, ln, sl, af);
    stg2(gB0, gB1, sB[1][1], wid, kb1);
    BAR(); LGKM0(); mfma8(acc, af, bfr, 1); BAR();
    // P2: kt0 ks1 mh0 | stage A-kh0(kt0+2)
    rdB4(sB[0][1], wn, ln, sl, bfr);
    rdA4(sA[0][1], 0, wm, ln, sl, af);
    stg2(gA0, gA1, sA[0][0], wid, kb2);
    BAR(); LGKM0(); mfma8(acc, af, bfr, 0); BAR();
    // P3: kt0 ks1 mh1 | stage B-kh0(kt0+2) | vmcnt
    rdA4(sA[0][1], 1, wm, ln, sl, af);
    stg2(gB0, gB1, sB[0][0], wid, kb2);
    BAR(); LGKM0(); mfma8(acc, af, bfr, 1);
    VMC4(); BAR();
    // P4: kt1 ks0 mh0 | stage A-kh1(kt0+2)
    rdB4(sB[1][0], wn, ln, sl, bfr);
    rdA4(sA[1][0], 0, wm, ln, sl, af);
    stg2(gA0, gA1, sA[0][1], wid, kb3);
    BAR(); LGKM0(); mfma8(acc, af, bfr, 0); BAR();
    // P5: kt1 ks0 mh1 | stage B-kh1(kt0+2)
    rdA4(sA[1][0], 1, wm, ln, sl, af);
    stg2(gB0, gB1, sB[0][1], wid, kb3);
    BAR(); LGKM0(); mfma8(acc, af, bfr, 1); BAR();
    // P6: kt1 ks1 mh0 | stage A-kh0(kt0+3)
    rdB4(sB[1][1], wn, ln, sl, bfr);
    rdA4(sA[1][1], 0, wm, ln, sl, af);
    stg2(gA0, gA1, sA[1][0], wid, kb4);
    BAR(); LGKM0(); mfma8(acc, af, bfr, 0); BAR();
    // P7: kt1 ks1 mh1 | stage B-kh0(kt0+3) | vmcnt
    rdA4(sA[1][1], 1, wm, ln, sl, af);
    stg2(gB0, gB1, sB[1][0], wid, kb4);
    BAR(); LGKM0(); mfma8(acc, af, bfr, 1);
    VMC4(); BAR();
  }
  // ---- final iteration: only P0/P1 stage (last K-tile's k-half1); drain at P3 ----
  {
    int kb1 = (kt0 + 1) * 64 + 32;
    rdB4(sB[0][0], wn, ln, sl, bfr);
    rdA4(sA[0][0], 0, wm, ln, sl, af);
    stg2(gA0, gA1, sA[1][1], wid, kb1);
    BAR(); LGKM0(); mfma8(acc, af, bfr, 0); BAR();
    rdA4(sA[0][0], 1, wm, ln, sl, af);
    stg2(gB0, gB1, sB[1][1], wid, kb1);
    BAR(); LGKM0(); mfma8(acc, af, bfr, 1); BAR();
    rdB4(sB[0][1], wn, ln, sl, bfr);
    rdA4(sA[0][1], 0, wm, ln, sl, af);
    BAR(); LGKM0(); mfma8(acc, af, bfr, 0); BAR();
    rdA4(sA[0][1], 1, wm, ln, sl, af);
    BAR(); LGKM0(); mfma8(acc, af, bfr, 1);
    VMC0(); BAR();
    rdB4(sB[1][0], wn, ln, sl, bfr);
    rdA4(sA[1][0], 0, wm, ln, sl, af);
    BAR(); LGKM0(); mfma8(acc, af, bfr, 0); BAR();
    rdA4(sA[1][0], 1, wm, ln, sl, af);
    BAR(); LGKM0(); mfma8(acc, af, bfr, 1); BAR();
    rdB4(sB[1][1], wn, ln, sl, bfr);
    rdA4(sA[1][1], 0, wm, ln, sl, af);
    BAR(); LGKM0(); mfma8(acc, af, bfr, 0); BAR();
    rdA4(sA[1][1], 1, wm, ln, sl, af);
    LGKM0(); mfma8(acc, af, bfr, 1);
  }

  // ---- epilogue: per-n terms + optional mask, bf16 store, GN partial stats ----
  const float* t1p = MASKED ? (t1 + (size_t)bz * N) : t1;
  float t1v[4], t2v[4];
#pragma unroll
  for (int ni = 0; ni < 4; ++ni) {
    int ncol = n0 + wn * 64 + ni * 16 + ln;
    t1v[ni] = t1p[ncol];
    t2v[ni] = MASKED ? t2[ncol] : 0.f;
  }
  float sp[4] = {0.f, 0.f, 0.f, 0.f}, ssp[4] = {0.f, 0.f, 0.f, 0.f};
  u16* ob = Out + (size_t)bz * M * N;
#pragma unroll
  for (int mi = 0; mi < 8; ++mi) {
    int mrow = m0 + wm * 128 + mi * 16 + lm * 4;
    float mka[4] = {1.f, 1.f, 1.f, 1.f};
    if constexpr (MASKED) {
      float4 mv = *(const float4*)(mkp + (size_t)bz * M + mrow);
      mka[0] = mv.x; mka[1] = mv.y; mka[2] = mv.z; mka[3] = mv.w;
    }
#pragma unroll
    for (int ni = 0; ni < 4; ++ni) {
      int ncol = n0 + wn * 64 + ni * 16 + ln;
#pragma unroll
      for (int r = 0; r < 4; ++r) {
        float v = acc[mi][ni][r] + t1v[ni];
        if constexpr (MASKED) v = v * mka[r] + t2v[ni];
        sp[ni] += v;
        ssp[ni] += v * v;
        ob[(size_t)(mrow + r) * N + ncol] = f2bf(v);
      }
    }
  }
#pragma unroll
  for (int ni = 0; ni < 4; ++ni) {
    float S = wred(sp[ni]);
    float SS = wred(ssp[ni]);
    if (lane == 0) {
      int grp = blockIdx.y * 16 + wn * 4 + ni;   // = channel/16
      atomicAdd(&sOut[bz * 32 + grp], S);
      atomicAdd(&ssOut[bz * 32 + grp], SS);
    }
  }
}

// ---------- fold GN1 affine into W2 (stats computed inline from s1/ss1):
// W2f[b][o][c] = bf16(W2[o][c]*gm1[b][c]), beta2[b][o] = sum_c W2[o][c]*bt1[b][c].
__global__ void __launch_bounds__(256) wfold2(const float* __restrict__ W2,
                                              const float* __restrict__ s1,
                                              const float* __restrict__ ss1,
                                              const float* __restrict__ g1,
                                              const float* __restrict__ be1,
                                              u16* __restrict__ W2f,
                                              float* __restrict__ beta2) {
  int w = blockIdx.x * 4 + (threadIdx.x >> 6);
  int lane = threadIdx.x & 63;
  int b = w >> 9, o = w & 511;
  int c0 = lane * 8;
  int g = c0 >> 4;                       // same group for c0..c0+7 (c0 % 8 == 0)
  const float cnt = 16.f * 2048.f;
  float mu = s1[b * 32 + g] / cnt;
  float var = ss1[b * 32 + g] / cnt - mu * mu;
  float inv = rsqrtf(var + 1e-5f);
  const float* wr = W2 + (size_t)o * 512 + c0;
  const float* gr = g1 + c0;
  const float* br = be1 + c0;
  float4 w0 = *(const float4*)wr, w1 = *(const float4*)(wr + 4);
  float4 q0 = *(const float4*)gr, q1 = *(const float4*)(gr + 4);
  float4 p0 = *(const float4*)br, p1 = *(const float4*)(br + 4);
  float wv[8] = {w0.x, w0.y, w0.z, w0.w, w1.x, w1.y, w1.z, w1.w};
  float gmv[8], btv[8];
  float qv[8] = {q0.x, q0.y, q0.z, q0.w, q1.x, q1.y, q1.z, q1.w};
  float pv[8] = {p0.x, p0.y, p0.z, p0.w, p1.x, p1.y, p1.z, p1.w};
#pragma unroll
  for (int j = 0; j < 8; ++j) {
    gmv[j] = qv[j] * inv;
    btv[j] = pv[j] - mu * gmv[j];
  }
  u32 ow[4];
  float acc = 0.f;
#pragma unroll
  for (int h = 0; h < 4; ++h) {
    float lo = wv[2 * h] * gmv[2 * h];
    float hi = wv[2 * h + 1] * gmv[2 * h + 1];
    ow[h] = (u32)f2bf(lo) | ((u32)f2bf(hi) << 16);
    acc += wv[2 * h] * btv[2 * h] + wv[2 * h + 1] * btv[2 * h + 1];
  }
  uint4 o4 = {ow[0], ow[1], ow[2], ow[3]};
  *(uint4*)(W2f + ((size_t)b * 512 + o) * 512 + c0) = o4;
  acc = wred(acc);
  if (lane == 0) beta2[(size_t)b * 512 + o] = acc;
}

// ---------- merged heads: z=0 cls (GN2 affine inline + sigmoid), z=1 text ----------
__global__ void __launch_bounds__(512) heads_all(const u16* __restrict__ X2,
                                                 const float* __restrict__ Wc,
                                                 const float* __restrict__ bcv,
                                                 const float* __restrict__ s2,
                                                 const float* __restrict__ ss2,
                                                 const float* __restrict__ g2,
                                                 const float* __restrict__ be2,
                                                 const float* __restrict__ masks,
                                                 const float* __restrict__ imgF,
                                                 const float* __restrict__ tproto,
                                                 float* __restrict__ clsL,
                                                 float* __restrict__ textL) {
  __shared__ float red[8][64][20];
  __shared__ float gmS[512], gdS[512];
  int tid = threadIdx.x;
  int tl = tid & 63;
  int ks = __builtin_amdgcn_readfirstlane(tid >> 6);
  int w = tid >> 6;
  int b = blockIdx.y;
  int t = blockIdx.x * 64 + tl;
  bool cls = (blockIdx.z == 0);
  if (cls) {
    int c = tid;
    int g = c >> 4;
    const float cnt = 16.f * 2048.f;
    float mu = s2[b * 32 + g] / cnt;
    float var = ss2[b * 32 + g] / cnt - mu * mu;
    float inv = rsqrtf(var + 1e-5f);
    float gm = g2[c] * inv;
    gmS[c] = gm;
    gdS[c] = be2[c] - mu * gm;
  }
  __syncthreads();
  float acc[20];
#pragma unroll
  for (int c = 0; c < 20; ++c) acc[c] = 0.f;
  if (cls) {
    const u16* xr = X2 + ((size_t)b * 2048 + t) * 512 + ks * 64;
    const float* Wk = Wc + ks * 64;
#pragma unroll
    for (int kk = 0; kk < 64; kk += 8) {
      float xv[8];
      uint4 v = *(const uint4*)(xr + kk);
      u32 wv[4] = {v.x, v.y, v.z, v.w};
#pragma unroll
      for (int h = 0; h < 4; ++h) {
        xv[2 * h] = bf2f((u16)(wv[h] & 0xffffu));
        xv[2 * h + 1] = bf2f((u16)(wv[h] >> 16));
      }
#pragma unroll
      for (int j = 0; j < 8; ++j)
        xv[j] = xv[j] * gmS[ks * 64 + kk + j] + gdS[ks * 64 + kk + j];
#pragma unroll
      for (int c = 0; c < 20; ++c) {
        const float* wr = &Wk[c * 512 + kk];
#pragma unroll
        for (int j = 0; j < 8; ++j) acc[c] += xv[j] * wr[j];
      }
    }
  } else {
    const float* xr = imgF + ((size_t)b * 2048 + t) * 512 + ks * 64;
    const float* Wk = tproto + ks * 64;
#pragma unroll
    for (int kk = 0; kk < 64; kk += 8) {
      float xv[8];
      float4 p0 = *(const float4*)(xr + kk);
      float4 p1 = *(const float4*)(xr + kk + 4);
      xv[0] = p0.x; xv[1] = p0.y; xv[2] = p0.z; xv[3] = p0.w;
      xv[4] = p1.x; xv[5] = p1.y; xv[6] = p1.z; xv[7] = p1.w;
#pragma unroll
      for (int c = 0; c < 20; ++c) {
        const float* wr = &Wk[c * 512 + kk];
#pragma unroll
        for (int j = 0; j < 8; ++j) acc[c] += xv[j] * wr[j];
      }
    }
  }
  // phase1: write partials (float4 x5), no atomics
#pragma unroll
  for (int c4 = 0; c4 < 5; ++c4) {
    float4 v = {acc[c4 * 4 + 0], acc[c4 * 4 + 1], acc[c4 * 4 + 2], acc[c4 * 4 + 3]};
    *(float4*)&red[w][tl][c4 * 4] = v;
  }
  __syncthreads();
  // phase2: tree-sum across 8 waves, finalize, store
  for (int idx = tid; idx < 1280; idx += 512) {
    int tl2 = idx / 20;
    int c = idx - tl2 * 20;
    float v = 0.f;
#pragma unroll
    for (int w2 = 0; w2 < 8; ++w2) v += red[w2][tl2][c];
    int t2 = blockIdx.x * 64 + tl2;
    if (cls) {
      float mk = masks[(size_t)b * 2048 + t2];
      v = v * mk + bcv[c];
      v = 1.f / (1.f + __expf(-v));
      clsL[((size_t)(b * 20 + c)) * 2048 + t2] = v;
    } else {
      textL[((size_t)(b * 20 + c)) * 2048 + t2] = v;
    }
  }
}

// ---------- top-k mean via exact MSB radix-select (4x 8-bit passes) ----------
__global__ void __launch_bounds__(256) topk_sel(const float* __restrict__ textL,
                                                const float* __restrict__ clsL,
                                                const float* __restrict__ img_masks,
                                                const float* __restrict__ masks,
                                                float* __restrict__ out) {
  __shared__ u32 keys[2048];
  __shared__ u32 hist[256];
  __shared__ u32 sel[2];
  __shared__ float rbuf[4], rbuf2[4];
  int bx = blockIdx.x;
  int head = bx / 320, rem = bx - head * 320;
  int b = rem / 20, c = rem - b * 20;
  int tid = threadIdx.x;
  const float* mk = head ? (masks + (size_t)b * 2048) : (img_masks + (size_t)b * 2048);
  float ls = 0.f;
  for (int i = tid; i < 2048; i += 256) ls += mk[i];
  ls = wred(ls);
  if ((tid & 63) == 0) rbuf[tid >> 6] = ls;
  const float* rowp = (head ? clsL : textL) + ((size_t)(b * 20 + c)) * 2048;
  for (int i = tid; i < 2048; i += 256) {
    u32 u = __float_as_uint(rowp[i]);
    u32 sgn = (u32)((int)u >> 31);
    keys[i] = u ^ (sgn | 0x80000000u);   // monotone flip: larger float -> larger uint
  }
  __syncthreads();
  int len = (int)(rbuf[0] + rbuf[1] + rbuf[2] + rbuf[3]);
  u32 k = (u32)(len >> 3);
  if (k < 1) k = 1;
  u32 want = k, prefix = 0;
#pragma unroll
  for (int byt = 3; byt >= 0; --byt) {
    int sh = byt * 8;
    hist[tid] = 0;
    __syncthreads();
    for (int i = tid; i < 2048; i += 256) {
      u32 kk = keys[i];
      bool match = (byt == 3) || ((kk >> (sh + 8)) == (prefix >> (sh + 8)));
      if (match) atomicAdd(&hist[(kk >> sh) & 0xffu], 1u);
    }
    __syncthreads();
    if (tid < 64) {   // single-wave suffix scan over 256 bins (descending)
      int r0 = tid * 4;
      u32 h0 = hist[255 - r0], h1 = hist[254 - r0], h2 = hist[253 - r0], h3 = hist[252 - r0];
      u32 p0 = h0, p1 = p0 + h1, p2 = p1 + h2, p3 = p2 + h3;
      u32 inc = p3;
#pragma unroll
      for (int off = 1; off < 64; off <<= 1) {
        u32 t = __shfl_up(inc, off, 64);
        if (tid >= off) inc += t;
      }
      u32 excl = inc - p3;
      u32 S0 = excl + p0, S1 = excl + p1, S2 = excl + p2, S3 = excl + p3;
      if (S0 >= want && excl < want) { sel[0] = (u32)(255 - r0); sel[1] = want - excl; }
      if (S1 >= want && S0 < want)   { sel[0] = (u32)(254 - r0); sel[1] = want - S0; }
      if (S2 >= want && S1 < want)   { sel[0] = (u32)(253 - r0); sel[1] = want - S1; }
      if (S3 >= want && S2 < want)   { sel[0] = (u32)(252 - r0); sel[1] = want - S2; }
    }
    __syncthreads();
    prefix |= sel[0] << sh;
    want = sel[1];
    __syncthreads();
  }
  // prefix == exact k-th largest key. sum strictly-greater + ties at threshold.
  float s = 0.f, cg = 0.f;
  for (int i = tid; i < 2048; i += 256) {
    u32 kk = keys[i];
    if (kk > prefix) {
      u32 u = (kk & 0x80000000u) ? (kk ^ 0x80000000u) : ~kk;
      s += __uint_as_float(u);
      cg += 1.f;
    }
  }
  s = wred(s);
  cg = wred(cg);
  if ((tid & 63) == 0) { rbuf[tid >> 6] = s; rbuf2[tid >> 6] = cg; }
  __syncthreads();
  if (tid == 0) {
    float S = rbuf[0] + rbuf[1] + rbuf[2] + rbuf[3];
    float CG = rbuf2[0] + rbuf2[1] + rbuf2[2] + rbuf2[3];
    u32 u = (prefix & 0x80000000u) ? (prefix ^ 0x80000000u) : ~prefix;
    float thr = __uint_as_float(u);
    S += ((float)k - CG) * thr;
    out[bx] = S / (float)k;
  }
}

// ---------- host ----------
extern "C" void kernel_launch(void* const* d_in, const int* in_sizes, int n_in,
                              void* d_out, int out_size, void* d_ws, size_t ws_size,
                              hipStream_t stream) {
  const float* F          = (const float*)d_in[0];   // [16,2048,2048]
  const float* masks      = (const float*)d_in[1];   // [16,1,2048]
  const float* text_proto = (const float*)d_in[2];   // [1,20,512]
  const float* img_feats  = (const float*)d_in[3];   // [16,2048,512]
  const float* img_masks  = (const float*)d_in[4];   // [16,2048]
  const float* W1 = (const float*)d_in[5];
  const float* b1 = (const float*)d_in[6];
  const float* g1 = (const float*)d_in[7];
  const float* be1 = (const float*)d_in[8];
  const float* W2 = (const float*)d_in[9];
  const float* b2 = (const float*)d_in[10];
  const float* g2 = (const float*)d_in[11];
  const float* be2 = (const float*)d_in[12];
  const float* Wc = (const float*)d_in[13];
  const float* bc = (const float*)d_in[14];
  float* out = (float*)d_out;

  const int T = 2048, Fd = 2048, O = 512;
  char* w = (char*)d_ws;
  // carve: W1b[2MB] (pad) x1[33.5MB] clsL[2.6MB] textL[2.6MB] (pad) | Ft[134MB] | ext
  u16* W1b     = (u16*)(w);
  u16* x1      = (u16*)(w + 2621440);
  float* clsL  = (float*)(w + 36175872);
  float* textL = (float*)(w + 38797312);
  const size_t oEnd0 = 41484288;
  const size_t ftBytes = (size_t)16 * T * Fd * 2;   // 134,217,728
  const size_t EXTRA = 8388608 + 32768 + 8192;      // W2f + beta2 + stats

  bool bigws = ws_size >= oEnd0 + ftBytes + EXTRA;
  char* ext = bigws ? (w + oEnd0 + ftBytes)
                    : (w + oEnd0 + (size_t)T * Fd * 2 + (size_t)16 * T * O * 2);
  u16* W2f     = (u16*)ext;
  float* beta2 = (float*)(ext + 8388608);
  float* sbase = beta2 + 16 * 512;   // s1|ss1|s2|ss2, 512 floats each
  float* s1 = sbase, *ss1 = sbase + 512, *s2 = sbase + 1024, *ss2 = sbase + 1536;

  const u16 *FtA, *FtA0;
  u16* x2;
  if (bigws) {
    u16* Ft = (u16*)(w + oEnd0);
    prep_kernel<<<dim3(32, 32, 17), 256, 0, stream>>>(F, Ft, W1, W1b, sbase);
    FtA = Ft; FtA0 = Ft; x2 = Ft;   // x2 aliases Ft (dead after GEMM1)
  } else {
    f2bf_kernel<<<1024, 256, 0, stream>>>(W1, W1b, (O * Fd) / 4);
    zinit<<<8, 256, 0, stream>>>(sbase, 2048);
    u16* ft0 = (u16*)(w + oEnd0);
    x2 = (u16*)(w + oEnd0 + (size_t)T * Fd * 2);
    for (int b = 0; b < 16; ++b) {
      u16* dst = (b == 0) ? ft0 : ((u16*)d_in[0]) + (size_t)b * T * Fd;
      transpose_bf16<<<dim3(32, 32, 1), 256, 0, stream>>>(F + (size_t)b * Fd * T, dst, 0, 0);
    }
    FtA = (const u16*)d_in[0]; FtA0 = ft0;
  }

  gemm8<false><<<dim3(8, 2, 16), 512, 0, stream>>>(FtA, FtA0, W1b, 0, b1, nullptr, nullptr,
                                                   s1, ss1, x1, 2048, 512, 2048);
  wfold2<<<2048, 256, 0, stream>>>(W2, s1, ss1, g1, be1, W2f, beta2);
  gemm8<true><<<dim3(8, 2, 16), 512, 0, stream>>>(x1, x1, W2f, (size_t)512 * 512, beta2, b2,
                                                  masks, s2, ss2, x2, 2048, 512, 512);
  heads_all<<<dim3(32, 16, 2), 512, 0, stream>>>(x2, Wc, bc, s2, ss2, g2, be2, masks,
                                                 img_feats, text_proto, clsL, textL);
  topk_sel<<<640, 256, 0, stream>>>(textL, clsL, img_masks, masks, out);
}